// Round 11
// baseline (6367.251 us; speedup 1.0000x reference)
//
#include <hip/hip_runtime.h>

typedef unsigned short u16;
typedef unsigned long long u64;
typedef short v8s __attribute__((ext_vector_type(8)));
typedef float v4f __attribute__((ext_vector_type(4)));
typedef unsigned v2u __attribute__((ext_vector_type(2)));

#define Bb 256
#define Tt 512
#define Dd 64
#define Hh 512
#define G4 2048

#define NGROUP 16    // batch groups (16 batch each), static mapping
#define NCHUNK 16    // hidden chunks per group (32 hidden units each)
#define BT 16
#define HC 32
#define NCOL 128     // local gate cols = 4 gates * HC

#define WHH_S 520   // 512 + 8 pad (bf16 elems)
#define WIH_S 72    // 64 + 8 pad
// whh 133120 + wih 18432 + 8192 partial-exchange = 159744 <= 160 KiB
#define SMEM_BYTES (NCOL*WHH_S*2 + NCOL*WIH_S*2 + 8192)

#define MFMA(a,b,c) __builtin_amdgcn_mfma_f32_16x16x32_bf16((a),(b),(c),0,0,0)

__device__ __forceinline__ u16 f2bf(float f) {
  unsigned u = __float_as_uint(f);
  unsigned r = (u + 0x7fffu + ((u >> 16) & 1u)) >> 16;
  return (u16)r;
}
__device__ __forceinline__ float bf2f(u16 v) {
  return __uint_as_float(((unsigned)v) << 16);
}
__device__ __forceinline__ float sigm(float x) { return 1.0f / (1.0f + __expf(-x)); }
__device__ __forceinline__ float tanh_f(float x) {
  float a = fabsf(x);
  float e = __expf(-2.0f * a);
  float r = (1.0f - e) / (1.0f + e);
  return copysignf(r, x);
}
__device__ __forceinline__ float softplus_f(float x) { return log1pf(__expf(x)); }

// ---------------------------------------------------------------- prep:
// x fp32 [B][T][D] -> bf16 [T][B][D]; zero 512 sync flags.
__global__ void k_prep(const float* __restrict__ x, u16* __restrict__ x_bf,
                       unsigned* __restrict__ flags)
{
  if (blockIdx.x < 2) {
    int i = blockIdx.x * 256 + threadIdx.x;
    if (i < NGROUP * NCHUNK * 2) flags[i] = 0u;
  }
  const int N4 = Tt * Bb * Dd / 4;
  int stride = gridDim.x * blockDim.x;
  for (int i = blockIdx.x * blockDim.x + threadIdx.x; i < N4; i += stride) {
    int idx = i * 4;
    int t = idx >> 14;          // / (B*D)
    int rem = idx & 16383;
    int b = rem >> 6;
    int d = rem & 63;
    float4 v = *(const float4*)(x + (size_t)b * (Tt * Dd) + t * Dd + d);
    unsigned lo = (unsigned)f2bf(v.x) | ((unsigned)f2bf(v.y) << 16);
    unsigned hi = (unsigned)f2bf(v.z) | ((unsigned)f2bf(v.w) << 16);
    *(uint2*)(x_bf + idx) = make_uint2(lo, hi);
  }
}

// ---------------------------------------------------------------- main:
// persistent LSTM. 256 blocks x 128 thr (2 waves), static group/chunk.
// K-SPLIT waves (zero redundant sc loads -> 4 MB/step, the structural
// minimum): wave wv loads only k-half [wv*256,(wv+1)*256) (chunks
// wv*8..wv*8+7), consumed EVENT-DRIVEN as producers land (r10 front-end),
// but computes ALL 8 gate-tiles on that half. Waves then exchange the
// partner-half partial accumulators via an 8 KB LDS buffer (fp32, 4B lane
// stride = conflict-free) with two symmetric __syncthreads, and each wave
// merges + updates ITS hidden-half in-register and publishes its own flag
// (r10 protocol). Work is symmetric (unlike r8) so barrier cost ~ 0.
// All exchange via L3 (sc0 sc1): placement-independent, no cache maint.
__global__ __launch_bounds__(128, 1) void lstm_main(
    const float* __restrict__ whh_mu, const float* __restrict__ whh_rho, const float* __restrict__ whh_eps,
    const float* __restrict__ wih_mu, const float* __restrict__ wih_rho, const float* __restrict__ wih_eps,
    const float* __restrict__ b_mu,  const float* __restrict__ b_rho,  const float* __restrict__ b_eps,
    const u16* __restrict__ x_bf, u16* __restrict__ h_buf, unsigned* __restrict__ flags)
{
  extern __shared__ char smem[];
  u16*   w_hh_lds = (u16*)smem;                     // [NCOL][WHH_S]
  u16*   w_ih_lds = w_hh_lds + NCOL * WHH_S;        // [NCOL][WIH_S]
  float* pb       = (float*)(w_ih_lds + NCOL * WIH_S); // [2][4][4][64] fp32

  const int tid   = threadIdx.x;
  const int g     = blockIdx.x & 15;   // batch group (static)
  const int chunk = blockIdx.x >> 4;   // hidden chunk (static)
  const int b0    = g * BT;
  const int j0    = chunk * HC;

  // ---- sample weight chunk into LDS: one column per thread (128 cols)
  {
    const int lc = tid;                                // 0..127
    const int gcol = (lc >> 5) * Hh + j0 + (lc & 31);  // global gate column
    #pragma unroll 4
    for (int k = 0; k < Hh; ++k) {
      int gi = k * G4 + gcol;
      float w = whh_mu[gi] + softplus_f(whh_rho[gi]) * whh_eps[gi];
      w_hh_lds[lc * WHH_S + k] = f2bf(w);
    }
    #pragma unroll 4
    for (int k = 0; k < Dd; ++k) {
      int gi = k * G4 + gcol;
      float w = wih_mu[gi] + softplus_f(wih_rho[gi]) * wih_eps[gi];
      w_ih_lds[lc * WIH_S + k] = f2bf(w);
    }
  }

  // ---- geometry: wave wv owns K-half wv; computes ALL 8 tiles on it.
  // tile rt = gt*2 + hidden-half; wave wv UPDATES hidden-half wv.
  const int lane = tid & 63;
  const int wv   = tid >> 6;
  const int ln   = lane & 15;
  const int q    = lane >> 4;
  const int ko   = q * 8;

  const u16* WhB[8]; const u16* WxB[8];
  #pragma unroll
  for (int rt = 0; rt < 8; ++rt) {
    WhB[rt] = w_hh_lds + (rt * 16 + ln) * WHH_S + wv * 256 + ko;
    WxB[rt] = w_ih_lds + (rt * 16 + ln) * WIH_S + wv * 32 + ko;
  }

  const int bat = b0 + ln;   // this lane's batch row (B-operand col)

  // ---- per-lane biases: own hidden jj = wv*16 + q*4 + r (4 units/gate)
  float bs[4][4];
  #pragma unroll
  for (int gt = 0; gt < 4; ++gt)
    #pragma unroll
    for (int r = 0; r < 4; ++r) {
      int colg = gt * Hh + j0 + wv * 16 + q * 4 + r;
      bs[gt][r] = b_mu[colg] + softplus_f(b_rho[colg]) * b_eps[colg];
    }

  float cc[4] = {0.f, 0.f, 0.f, 0.f};
  // flags layout: fgrp2[w*16 + c] = flag of (chunk c, producer-wave w)
  unsigned* const fgrp2 = flags + g * (NCHUNK * 2);
  // lanes 0..15 poll the 16 flags of this wave's 8 chunks (both producers)
  const unsigned* fp2 = fgrp2 + ((lane >> 3) & 1) * 16 + wv * 8 + (lane & 7);
  __syncthreads();   // weights-in-LDS ready (one-time)

  for (int t = 0; t < Tt; ++t) {
    v4f acc[8];
    #pragma unroll
    for (int rt = 0; rt < 8; ++rt) acc[rt] = (v4f){0.f,0.f,0.f,0.f};

    // ---- input projection, this wave's K-half of D (h-independent)
    {
      const u16* xb = x_bf + (size_t)t * (Bb * Dd) + bat * Dd + wv * 32 + ko;
      v8s xf = *(const v8s*)xb;
      #pragma unroll
      for (int rt = 0; rt < 8; ++rt)
        acc[rt] = MFMA(*(const v8s*)WxB[rt], xf, acc[rt]);
    }

    if (t > 0) {
      // ---- event-driven recurrent GEMM over this wave's 8 k-slices
      const u16* hb = h_buf + (t & 1) * (Bb * Hh) + bat * Hh + wv * 256 + ko;
      unsigned done = 0, todo = 0;
      v8s buf[8];
      for (;;) {
        unsigned pv = 0;
        bool needPoll = (done | todo) != 0xFFu;
        if (needPoll) {
          asm volatile("global_load_dword %0, %1, off sc0 sc1"
                       : "=v"(pv) : "v"(fp2));
        }
        #pragma unroll
        for (int c = 0; c < 8; ++c)
          if (todo & (1u << c)) {
            asm volatile("global_load_dwordx4 %0, %1, off offset:%c2 sc0 sc1"
                         : "=v"(buf[c]) : "v"(hb), "i"(c * 64));
          }
        asm volatile("s_waitcnt vmcnt(0)");
        // r9-class fix: pin asm-load results after the shared drain
        if (needPoll) {
          asm volatile("" : "+v"(pv));
        }
        #pragma unroll
        for (int c = 0; c < 8; ++c)
          if (todo & (1u << c)) {
            asm volatile("" : "+v"(buf[c]));
            #pragma unroll
            for (int rt = 0; rt < 8; ++rt)
              acc[rt] = MFMA(*(const v8s*)(WhB[rt] + c * 32), buf[c], acc[rt]);
          }
        done |= todo;
        if (done == 0xFFu) break;
        u64 bal = __ballot((int)(pv >= (unsigned)t));
        unsigned lo = (unsigned)bal;
        unsigned ready = lo & (lo >> 8) & 0xFFu;   // both producers of chunk
        todo = ready & ~done;
      }
    }

    // ---- cross-wave partial exchange (8 KB LDS, 4B lane stride):
    // write partner-half tiles, barrier, merge partner's partials of own
    // tiles, barrier (protects slot reuse next step).
    #pragma unroll
    for (int gt = 0; gt < 4; ++gt) {
      int pt = gt * 2 + (1 - wv);              // partner-half tile
      #pragma unroll
      for (int r = 0; r < 4; ++r)
        pb[((wv * 4 + gt) * 4 + r) * 64 + lane] = acc[pt][r];
    }
    __syncthreads();
    v4f ac[4];
    #pragma unroll
    for (int gt = 0; gt < 4; ++gt) {
      int ot = gt * 2 + wv;                    // own-half tile
      #pragma unroll
      for (int r = 0; r < 4; ++r)
        ac[gt][r] = acc[ot][r] + pb[(((1 - wv) * 4 + gt) * 4 + r) * 64 + lane];
    }
    __syncthreads();

    // ---- LSTM update fully in-register; one 8B sc store of this wave's
    // 4 hidden units for batch bat.
    {
      u16 hv[4];
      #pragma unroll
      for (int r = 0; r < 4; ++r) {
        float ig = sigm  (ac[0][r] + bs[0][r]);
        float fg = sigm  (ac[1][r] + bs[1][r]);
        float gg = tanh_f(ac[2][r] + bs[2][r]);
        float og = sigm  (ac[3][r] + bs[3][r]);
        cc[r] = fg * cc[r] + ig * gg;
        hv[r] = f2bf(og * tanh_f(cc[r]));
      }
      v2u qv;
      qv[0] = (unsigned)hv[0] | ((unsigned)hv[1] << 16);
      qv[1] = (unsigned)hv[2] | ((unsigned)hv[3] << 16);
      u16* hp = h_buf + ((t + 1) & 1) * (Bb * Hh) + bat * Hh
              + j0 + wv * 16 + q * 4;
      asm volatile("global_store_dwordx2 %0, %1, off sc0 sc1"
                   :: "v"(hp), "v"(qv) : "memory");
    }

    // ---- publish (per wave, independent): drain h stores, set own flag
    asm volatile("s_waitcnt vmcnt(0)" ::: "memory");
    if (lane == 0) {
      unsigned tv = (unsigned)(t + 1);
      unsigned* fq = &fgrp2[wv * 16 + chunk];
      asm volatile("global_store_dword %0, %1, off sc0 sc1"
                   :: "v"(fq), "v"(tv) : "memory");
    }
  }
}

// ---------------------------------------------------------------- epilogue:
// out[b] = h_last[b,:] . lin_w + lin_b   (h_last in h_buf[0], since T even)
__global__ void k_out(const u16* __restrict__ h, const float* __restrict__ lw,
                      const float* __restrict__ lb, float* __restrict__ out)
{
  int b = blockIdx.x * 64 + threadIdx.x;
  if (b >= Bb) return;
  const u16* hr = h + b * Hh;
  float acc = 0.f;
  #pragma unroll 8
  for (int k = 0; k < Hh; ++k) acc += bf2f(hr[k]) * lw[k];
  out[b] = acc + lb[0];
}

extern "C" void kernel_launch(void* const* d_in, const int* in_sizes, int n_in,
                              void* d_out, int out_size, void* d_ws, size_t ws_size,
                              hipStream_t stream)
{
  (void)in_sizes; (void)n_in; (void)out_size; (void)ws_size;
  const float* x       = (const float*)d_in[0];
  const float* wih_mu  = (const float*)d_in[1];
  const float* wih_rho = (const float*)d_in[2];
  const float* wih_eps = (const float*)d_in[3];
  const float* whh_mu  = (const float*)d_in[4];
  const float* whh_rho = (const float*)d_in[5];
  const float* whh_eps = (const float*)d_in[6];
  const float* b_mu    = (const float*)d_in[7];
  const float* b_rho   = (const float*)d_in[8];
  const float* b_eps   = (const float*)d_in[9];
  const float* lin_w   = (const float*)d_in[10];
  const float* lin_b   = (const float*)d_in[11];
  float* out = (float*)d_out;

  // workspace layout
  u16* x_bf  = (u16*)d_ws;                       // T*B*D bf16  = 16 MB
  u16* h_buf = x_bf + (size_t)Tt * Bb * Dd;      // 2*B*H bf16  = 512 KB
  unsigned* flags = (unsigned*)(h_buf + 2 * Bb * Hh);  // 512 flags

  k_prep<<<2048, 256, 0, stream>>>(x, x_bf, flags);

  hipFuncSetAttribute(reinterpret_cast<const void*>(lstm_main),
                      hipFuncAttributeMaxDynamicSharedMemorySize, SMEM_BYTES);
  lstm_main<<<NGROUP * NCHUNK, 128, SMEM_BYTES, stream>>>(
      whh_mu, whh_rho, whh_eps, wih_mu, wih_rho, wih_eps,
      b_mu, b_rho, b_eps, x_bf, h_buf, flags);

  k_out<<<(Bb + 63) / 64, 64, 0, stream>>>(h_buf, lin_w, lin_b, out);
}